// Round 6
// baseline (419.534 us; speedup 1.0000x reference)
//
#include <hip/hip_runtime.h>

#define DEV static __device__ __forceinline__

typedef __bf16 bf16x8 __attribute__((ext_vector_type(8)));
typedef __bf16 bf16x4 __attribute__((ext_vector_type(4)));
typedef float  f32x4  __attribute__((ext_vector_type(4)));

DEV bf16x8 ld8(const __bf16* p) { return *reinterpret_cast<const bf16x8*>(p); }
DEV bf16x4 ld4(const __bf16* p) { return *reinterpret_cast<const bf16x4*>(p); }

DEV f32x4 mfma16(bf16x8 a, bf16x8 b, f32x4 c) {
  return __builtin_amdgcn_mfma_f32_16x16x32_bf16(a, b, c, 0, 0, 0);
}
// K=16 PV step emulated on the K=32 unit: lower 4 slots carry data, upper 4
// are zero in BOTH operands (0 * garbage could be NaN).
DEV f32x4 mfma_pv(bf16x4 a, bf16x4 b, f32x4 c) {
  bf16x8 av = {a[0], a[1], a[2], a[3], (__bf16)0.f, (__bf16)0.f, (__bf16)0.f, (__bf16)0.f};
  bf16x8 bv = {b[0], b[1], b[2], b[3], (__bf16)0.f, (__bf16)0.f, (__bf16)0.f, (__bf16)0.f};
  return __builtin_amdgcn_mfma_f32_16x16x32_bf16(av, bv, c, 0, 0, 0);
}

// B=2, S=2048, D=768, H=12, HD=64
#define SEQ 2048
#define DIM 768
#define NH  12
#define HDIM 64

// given chunk id cid (within one bh) and chunk size CH (in 64-k-tiles),
// find q-tile qt and first k-tile t0. lower-triangle chunks only.
DEV void decode_chunk(int cid, int CH, int& qt, int& t0) {
  int q = 0, rem = cid;
  while (true) {
    int nc = (q + CH) / CH;  // ceil((q+1)/CH)
    if (rem < nc) break;
    rem -= nc; ++q;
  }
  qt = q; t0 = rem * CH;
}

// ---------------------------------------------------------------------------
// prep_wt: transpose+convert the 4 weight matrices to bf16 [out_n][in_k].
// ---------------------------------------------------------------------------
__global__ __launch_bounds__(256) void prep_wt(
    const float* __restrict__ Wq, const float* __restrict__ Wk,
    const float* __restrict__ Wv, const float* __restrict__ Wo,
    __bf16* __restrict__ WbT) {
  __shared__ float T[64][65];
  const int z = blockIdx.z;
  const float* W = (z == 0) ? Wq : (z == 1) ? Wk : (z == 2) ? Wv : Wo;
  const int kb = blockIdx.x * 64, nb = blockIdx.y * 64;
  const int t = threadIdx.x, r = t >> 2, c4 = (t & 3) * 16;
  #pragma unroll
  for (int j = 0; j < 16; j += 4) {
    f32x4 v = *(const f32x4*)(W + (size_t)(kb + r) * DIM + nb + c4 + j);
    T[r][c4 + j]     = v[0]; T[r][c4 + j + 1] = v[1];
    T[r][c4 + j + 2] = v[2]; T[r][c4 + j + 3] = v[3];
  }
  __syncthreads();
  bf16x8 o0, o1;
  #pragma unroll
  for (int j = 0; j < 8; ++j) {
    o0[j] = (__bf16)T[c4 + j][r];
    o1[j] = (__bf16)T[c4 + 8 + j][r];
  }
  __bf16* dst = WbT + (size_t)z * DIM * DIM + (size_t)(nb + r) * DIM + kb + c4;
  *(bf16x8*)dst = o0;
  *(bf16x8*)(dst + 8) = o1;
}

// ---------------------------------------------------------------------------
// shared GEMM tile body: A fp32, B pre-transposed bf16 [n][k].
// ---------------------------------------------------------------------------
DEV void gemm_tile(const float* __restrict__ Af, const __bf16* __restrict__ Bt,
                   const float* __restrict__ bias, void* __restrict__ outp,
                   const int mode, const float scale,
                   const int mbase, const int nbase) {
  __shared__ __bf16 As[64][72];
  __shared__ __bf16 Bs[64][72];

  const int tid  = threadIdx.x;
  const int l    = tid & 63;
  const int w    = tid >> 6;
  const int lrow = l & 15;
  const int lk8  = (l >> 4) * 8;
  const int wrow = (w >> 1) * 32, wcol = (w & 1) * 32;

  f32x4 acc[2][2] = {};

  const int arow = tid >> 2;
  const int acol = (tid & 3) * 16;

  for (int kk = 0; kk < DIM; kk += 64) {
    {
      const float* src = Af + (size_t)(mbase + arow) * DIM + kk + acol;
      f32x4 f0 = *(const f32x4*)(src);
      f32x4 f1 = *(const f32x4*)(src + 4);
      f32x4 f2 = *(const f32x4*)(src + 8);
      f32x4 f3 = *(const f32x4*)(src + 12);
      bf16x8 v0, v1;
      #pragma unroll
      for (int j = 0; j < 4; ++j) {
        v0[j] = (__bf16)f0[j]; v0[4 + j] = (__bf16)f1[j];
        v1[j] = (__bf16)f2[j]; v1[4 + j] = (__bf16)f3[j];
      }
      *(bf16x8*)&As[arow][acol]     = v0;
      *(bf16x8*)&As[arow][acol + 8] = v1;
    }
    {
      const __bf16* bsrc = Bt + (size_t)(nbase + arow) * DIM + kk + acol;
      *(bf16x8*)&Bs[arow][acol]     = ld8(bsrc);
      *(bf16x8*)&Bs[arow][acol + 8] = ld8(bsrc + 8);
    }
    __syncthreads();
    #pragma unroll
    for (int kc = 0; kc < 2; ++kc) {
      bf16x8 a0 = ld8(&As[wrow + lrow][kc * 32 + lk8]);
      bf16x8 a1 = ld8(&As[wrow + 16 + lrow][kc * 32 + lk8]);
      bf16x8 b0 = ld8(&Bs[wcol + lrow][kc * 32 + lk8]);
      bf16x8 b1 = ld8(&Bs[wcol + 16 + lrow][kc * 32 + lk8]);
      acc[0][0] = mfma16(a0, b0, acc[0][0]);
      acc[0][1] = mfma16(a0, b1, acc[0][1]);
      acc[1][0] = mfma16(a1, b0, acc[1][0]);
      acc[1][1] = mfma16(a1, b1, acc[1][1]);
    }
    __syncthreads();
  }

  #pragma unroll
  for (int mi = 0; mi < 2; ++mi)
  #pragma unroll
  for (int ni = 0; ni < 2; ++ni) {
    const int n  = nbase + wcol + ni * 16 + lrow;
    const float bn = bias[n];
    const int hh = n >> 6, hd = n & 63;
    #pragma unroll
    for (int r = 0; r < 4; ++r) {
      const int m = mbase + wrow + mi * 16 + (l >> 4) * 4 + r;
      const float v = (acc[mi][ni][r] + bn) * scale;
      const int bb = m >> 11, s = m & (SEQ - 1);
      if (mode == 0) {
        ((__bf16*)outp)[(((size_t)(bb * NH + hh) * SEQ) + s) * HDIM + hd] = (__bf16)v;
      } else if (mode == 1) {
        ((__bf16*)outp)[(((size_t)(bb * NH + hh) * HDIM) + hd) * SEQ + s] = (__bf16)v;
      } else {
        ((float*)outp)[(size_t)m * DIM + n] = v;
      }
    }
  }
}

__global__ __launch_bounds__(256) void qkv_gemm(
    const float* __restrict__ x, const __bf16* __restrict__ WbT,
    const float* __restrict__ bq, const float* __restrict__ bk,
    const float* __restrict__ bv,
    __bf16* __restrict__ Qb, __bf16* __restrict__ Kb, __bf16* __restrict__ Vt) {
  const int z = blockIdx.z;
  const __bf16* Bt = WbT + (size_t)z * DIM * DIM;
  const float* bs = (z == 0) ? bq : (z == 1) ? bk : bv;
  void* o = (z == 0) ? (void*)Qb : (z == 1) ? (void*)Kb : (void*)Vt;
  const float sc = (z == 0) ? 0.125f : 1.f;  // fold 1/sqrt(HD) into Q
  gemm_tile(x, Bt, bs, o, (z == 2) ? 1 : 0, sc, blockIdx.y * 64, blockIdx.x * 64);
}

__global__ __launch_bounds__(256) void out_gemm(
    const float* __restrict__ A, const __bf16* __restrict__ WbT,
    const float* __restrict__ bo, float* __restrict__ out) {
  gemm_tile(A, WbT + (size_t)3 * DIM * DIM, bo, out, 2, 1.f,
            blockIdx.y * 64, blockIdx.x * 64);
}

// ---------------------------------------------------------------------------
__global__ __launch_bounds__(256) void zero_f32(float* __restrict__ p, int n4) {
  const f32x4 zv = {0.f, 0.f, 0.f, 0.f};
  int i = blockIdx.x * 256 + threadIdx.x;
  const int stride = gridDim.x * 256;
  for (; i < n4; i += stride) ((f32x4*)p)[i] = zv;
}

// ---------------------------------------------------------------------------
// attn_sums: swapped-operand QK^T (S^T frags: lane owns q=lrow, k=g*4+r).
// Per-lane local sum over 16 k, then shfl_xor(16,32) across g, one atomic
// per lane. grid = 24 * 144 blocks of 256.
// ---------------------------------------------------------------------------
__global__ __launch_bounds__(256) void attn_sums(
    const __bf16* __restrict__ Q, const __bf16* __restrict__ K,
    float* __restrict__ sums) {
  const int tid = threadIdx.x, l = tid & 63, w = tid >> 6;
  const int lrow = l & 15, lk8 = (l >> 4) * 8, g = l >> 4;
  const int lin = blockIdx.x;
  const int C = 144;
  const int bh = (lin & 7) * 3 + (lin >> 3) / C;
  const int cid = (lin >> 3) % C;
  int qt, t0; decode_chunk(cid, 4, qt, t0);
  const int t1 = (t0 + 4 < qt + 1) ? t0 + 4 : qt + 1;
  const int qw = qt * 64 + w * 16;
  const int q  = qw + lrow;   // this lane's q row (S^T layout)

  const __bf16* Qh = Q + (size_t)bh * SEQ * HDIM;
  const __bf16* Kh = K + (size_t)bh * SEQ * HDIM;
  const bf16x8 bq0 = ld8(Qh + (size_t)q * HDIM + lk8);        // B operand (Q)
  const bf16x8 bq1 = ld8(Qh + (size_t)q * HDIM + 32 + lk8);

  float ssum = 0.f;
  for (int t = t0; t < t1; ++t) {
    const int kb = t * 64;
    #pragma unroll
    for (int nt = 0; nt < 4; ++nt) {
      const int krow = kb + nt * 16 + lrow;                   // A operand (K)
      const bf16x8 ak0 = ld8(Kh + (size_t)krow * HDIM + lk8);
      const bf16x8 ak1 = ld8(Kh + (size_t)krow * HDIM + 32 + lk8);
      f32x4 s0 = {0.f, 0.f, 0.f, 0.f}, s1 = {0.f, 0.f, 0.f, 0.f};
      s0 = mfma16(ak0, bq0, s0);
      s1 = mfma16(ak1, bq1, s1);
      const int k0 = kb + nt * 16 + g * 4;                    // lane's k base
      if (t < qt || k0 + 3 <= q) {  // fully unmasked
        #pragma unroll
        for (int r = 0; r < 4; ++r) ssum += __expf(s0[r] + s1[r]);
      } else {
        #pragma unroll
        for (int r = 0; r < 4; ++r)
          ssum += (k0 + r <= q) ? __expf(s0[r] + s1[r]) : 0.f;
      }
    }
  }
  ssum += __shfl_xor(ssum, 16);
  ssum += __shfl_xor(ssum, 32);
  if (g == 0) unsafeAtomicAdd(&sums[bh * SEQ + q], ssum);
}

// ---------------------------------------------------------------------------
// attn_wpv: swapped-operand QK^T -> S^T frags; normalized weights stored
// DIRECTLY from registers as f32x4 (lane owns Wg[q][k0..k0+3]); PV via
// zero-padded K=32 MFMA using the lane's own 4 P values as its A-frag (no
// cross-lane redistribution, no LDS, no barriers). grid = 24 * 80 blocks.
// ---------------------------------------------------------------------------
__global__ __launch_bounds__(256) void attn_wpv(
    const __bf16* __restrict__ Q, const __bf16* __restrict__ K,
    const __bf16* __restrict__ VT, const float* __restrict__ sums,
    float* __restrict__ Wout, float* __restrict__ AOf) {
  const int tid = threadIdx.x, l = tid & 63, w = tid >> 6;
  const int lrow = l & 15, lk8 = (l >> 4) * 8, g = l >> 4;
  const int lin = blockIdx.x;
  const int C = 80;
  const int bh = (lin & 7) * 3 + (lin >> 3) / C;
  const int cid = (lin >> 3) % C;
  int qt, t0; decode_chunk(cid, 8, qt, t0);
  const int t1 = (t0 + 8 < qt + 1) ? t0 + 8 : qt + 1;
  const int bb = bh / NH, hh = bh % NH;
  const int qw = qt * 64 + w * 16;
  const int q  = qw + lrow;   // lane's q row

  const __bf16* Qh = Q + (size_t)bh * SEQ * HDIM;
  const __bf16* Kh = K + (size_t)bh * SEQ * HDIM;
  const __bf16* Vh = VT + (size_t)bh * HDIM * SEQ;
  float* Wg = Wout + (size_t)bh * SEQ * SEQ;

  const bf16x8 bq0 = ld8(Qh + (size_t)q * HDIM + lk8);
  const bf16x8 bq1 = ld8(Qh + (size_t)q * HDIM + 32 + lk8);
  const float inv = 1.f / sums[bh * SEQ + q];

  f32x4 acco[4] = {};  // O D-frag: row=q'=g*4+r, col=d=dt*16+lrow
  for (int t = t0; t < t1; ++t) {
    const int kb = t * 64;
    #pragma unroll
    for (int nt = 0; nt < 4; ++nt) {
      const int krow = kb + nt * 16 + lrow;
      const bf16x8 ak0 = ld8(Kh + (size_t)krow * HDIM + lk8);
      const bf16x8 ak1 = ld8(Kh + (size_t)krow * HDIM + 32 + lk8);
      f32x4 s0 = {0.f, 0.f, 0.f, 0.f}, s1 = {0.f, 0.f, 0.f, 0.f};
      s0 = mfma16(ak0, bq0, s0);
      s1 = mfma16(ak1, bq1, s1);
      const int k0 = kb + nt * 16 + g * 4;
      f32x4 pv;
      if (t < qt || k0 + 3 <= q) {
        #pragma unroll
        for (int r = 0; r < 4; ++r) pv[r] = __expf(s0[r] + s1[r]) * inv;
      } else {
        #pragma unroll
        for (int r = 0; r < 4; ++r)
          pv[r] = (k0 + r <= q) ? __expf(s0[r] + s1[r]) * inv : 0.f;
      }
      // direct vectorized weight store: lane owns Wg[q][k0..k0+3]
      *(f32x4*)&Wg[(size_t)q * SEQ + k0] = pv;
      // PV: lane's own 4 P values = its A-frag (row=q, slots g*8+0..3)
      bf16x4 pa;
      #pragma unroll
      for (int r = 0; r < 4; ++r) pa[r] = (__bf16)pv[r];
      #pragma unroll
      for (int dt = 0; dt < 4; ++dt) {
        const bf16x4 vb = ld4(Vh + (size_t)(dt * 16 + lrow) * SEQ + k0);
        acco[dt] = mfma_pv(pa, vb, acco[dt]);
      }
    }
  }

  #pragma unroll
  for (int dt = 0; dt < 4; ++dt)
    #pragma unroll
    for (int r = 0; r < 4; ++r)
      unsafeAtomicAdd(
          &AOf[(size_t)(bb * SEQ + qw + g * 4 + r) * DIM + hh * HDIM + dt * 16 + lrow],
          acco[dt][r]);
}

// ---------------------------------------------------------------------------
// zfill: zero upper-triangle weight region. grid (8 col-chunks, 32 qt, 24 bh).
// ---------------------------------------------------------------------------
__global__ __launch_bounds__(256) void zfill(float* __restrict__ Wout) {
  const int c8 = blockIdx.x, qt = blockIdx.y, bh = blockIdx.z;
  const int kstart = (qt + 1) * 64;
  if (kstart >= SEQ) return;
  const int wseg = (SEQ - kstart) >> 3;
  const int c0 = kstart + c8 * wseg;
  const int vpr = wseg >> 2;
  float* base = Wout + (size_t)bh * SEQ * SEQ + (size_t)qt * 64 * SEQ;
  const int tid = threadIdx.x;
  const f32x4 zv = {0.f, 0.f, 0.f, 0.f};
  for (int rb = tid >> 3; rb < 64; rb += 32)
    for (int cb = tid & 7; cb < vpr; cb += 8)
      *(f32x4*)&base[(size_t)rb * SEQ + c0 + cb * 4] = zv;
}

// ---------------------------------------------------------------------------
extern "C" void kernel_launch(void* const* d_in, const int* in_sizes, int n_in,
                              void* d_out, int out_size, void* d_ws, size_t ws_size,
                              hipStream_t stream) {
  const float* x  = (const float*)d_in[0];
  const float* Wq = (const float*)d_in[2];
  const float* bq = (const float*)d_in[3];
  const float* Wk = (const float*)d_in[4];
  const float* bk = (const float*)d_in[5];
  const float* Wv = (const float*)d_in[6];
  const float* bv = (const float*)d_in[7];
  const float* Wo = (const float*)d_in[8];
  const float* bo = (const float*)d_in[9];

  char* wsb = (char*)d_ws;
  __bf16* Qb   = (__bf16*)(wsb);                 // [B,H,S,HD] bf16   6 MB
  __bf16* Kb   = (__bf16*)(wsb + 6291456);       // [B,H,S,HD] bf16   6 MB
  __bf16* Vt   = (__bf16*)(wsb + 12582912);      // [B,H,HD,S] bf16   6 MB
  float*  AOf  = (float*)(wsb + 18874368);       // [B*S, D] fp32    12 MB
  float*  sums = (float*)(wsb + 31457280);       // [24,2048] fp32  0.2 MB
  __bf16* WbT  = (__bf16*)(wsb + 31653888);      // [4,768,768] bf16 4.7 MB

  float* out   = (float*)d_out;                  // [2,2048,768] fp32
  float* attnW = out + 3145728;                  // [2,12,2048,2048] fp32

  zero_f32<<<1024, 256, 0, stream>>>(AOf, (3145728 + 49152) / 4);
  prep_wt<<<dim3(12, 12, 4), 256, 0, stream>>>(Wq, Wk, Wv, Wo, WbT);
  qkv_gemm<<<dim3(12, 64, 3), 256, 0, stream>>>(x, WbT, bq, bk, bv, Qb, Kb, Vt);
  attn_sums<<<24 * 144, 256, 0, stream>>>(Qb, Kb, sums);
  zfill<<<dim3(8, 32, 24), 256, 0, stream>>>(attnW);
  attn_wpv<<<24 * 80, 256, 0, stream>>>(Qb, Kb, Vt, sums, attnW, AOf);
  out_gemm<<<dim3(12, 64), 256, 0, stream>>>(AOf, WbT, bo, out);
}

// Round 7
// 349.310 us; speedup vs baseline: 1.2010x; 1.2010x over previous
//
#include <hip/hip_runtime.h>

#define DEV static __device__ __forceinline__

typedef __bf16 bf16x8 __attribute__((ext_vector_type(8)));
typedef float  f32x4  __attribute__((ext_vector_type(4)));

DEV bf16x8 ld8(const __bf16* p) { return *reinterpret_cast<const bf16x8*>(p); }

DEV f32x4 mfma16(bf16x8 a, bf16x8 b, f32x4 c) {
  return __builtin_amdgcn_mfma_f32_16x16x32_bf16(a, b, c, 0, 0, 0);
}

// B=2, S=2048, D=768, H=12, HD=64
#define SEQ 2048
#define DIM 768
#define NH  12
#define HDIM 64

// given chunk id cid (within one bh) and chunk size CH (in 64-k-tiles),
// find q-tile qt and first k-tile t0. lower-triangle chunks only.
DEV void decode_chunk(int cid, int CH, int& qt, int& t0) {
  int q = 0, rem = cid;
  while (true) {
    int nc = (q + CH) / CH;  // ceil((q+1)/CH)
    if (rem < nc) break;
    rem -= nc; ++q;
  }
  qt = q; t0 = rem * CH;
}

// ---------------------------------------------------------------------------
// prep_wt: transpose+convert the 4 weight matrices to bf16 [out_n][in_k].
// ---------------------------------------------------------------------------
__global__ __launch_bounds__(256) void prep_wt(
    const float* __restrict__ Wq, const float* __restrict__ Wk,
    const float* __restrict__ Wv, const float* __restrict__ Wo,
    __bf16* __restrict__ WbT) {
  __shared__ float T[64][65];
  const int z = blockIdx.z;
  const float* W = (z == 0) ? Wq : (z == 1) ? Wk : (z == 2) ? Wv : Wo;
  const int kb = blockIdx.x * 64, nb = blockIdx.y * 64;
  const int t = threadIdx.x, r = t >> 2, c4 = (t & 3) * 16;
  #pragma unroll
  for (int j = 0; j < 16; j += 4) {
    f32x4 v = *(const f32x4*)(W + (size_t)(kb + r) * DIM + nb + c4 + j);
    T[r][c4 + j]     = v[0]; T[r][c4 + j + 1] = v[1];
    T[r][c4 + j + 2] = v[2]; T[r][c4 + j + 3] = v[3];
  }
  __syncthreads();
  bf16x8 o0, o1;
  #pragma unroll
  for (int j = 0; j < 8; ++j) {
    o0[j] = (__bf16)T[c4 + j][r];
    o1[j] = (__bf16)T[c4 + 8 + j][r];
  }
  __bf16* dst = WbT + (size_t)z * DIM * DIM + (size_t)(nb + r) * DIM + kb + c4;
  *(bf16x8*)dst = o0;
  *(bf16x8*)(dst + 8) = o1;
}

// ---------------------------------------------------------------------------
// shared GEMM tile body: A fp32, B pre-transposed bf16 [n][k].
// ---------------------------------------------------------------------------
DEV void gemm_tile(const float* __restrict__ Af, const __bf16* __restrict__ Bt,
                   const float* __restrict__ bias, void* __restrict__ outp,
                   const int mode, const float scale,
                   const int mbase, const int nbase) {
  __shared__ __bf16 As[64][72];
  __shared__ __bf16 Bs[64][72];

  const int tid  = threadIdx.x;
  const int l    = tid & 63;
  const int w    = tid >> 6;
  const int lrow = l & 15;
  const int lk8  = (l >> 4) * 8;
  const int wrow = (w >> 1) * 32, wcol = (w & 1) * 32;

  f32x4 acc[2][2] = {};

  const int arow = tid >> 2;
  const int acol = (tid & 3) * 16;

  for (int kk = 0; kk < DIM; kk += 64) {
    {
      const float* src = Af + (size_t)(mbase + arow) * DIM + kk + acol;
      f32x4 f0 = *(const f32x4*)(src);
      f32x4 f1 = *(const f32x4*)(src + 4);
      f32x4 f2 = *(const f32x4*)(src + 8);
      f32x4 f3 = *(const f32x4*)(src + 12);
      bf16x8 v0, v1;
      #pragma unroll
      for (int j = 0; j < 4; ++j) {
        v0[j] = (__bf16)f0[j]; v0[4 + j] = (__bf16)f1[j];
        v1[j] = (__bf16)f2[j]; v1[4 + j] = (__bf16)f3[j];
      }
      *(bf16x8*)&As[arow][acol]     = v0;
      *(bf16x8*)&As[arow][acol + 8] = v1;
    }
    {
      const __bf16* bsrc = Bt + (size_t)(nbase + arow) * DIM + kk + acol;
      *(bf16x8*)&Bs[arow][acol]     = ld8(bsrc);
      *(bf16x8*)&Bs[arow][acol + 8] = ld8(bsrc + 8);
    }
    __syncthreads();
    #pragma unroll
    for (int kc = 0; kc < 2; ++kc) {
      bf16x8 a0 = ld8(&As[wrow + lrow][kc * 32 + lk8]);
      bf16x8 a1 = ld8(&As[wrow + 16 + lrow][kc * 32 + lk8]);
      bf16x8 b0 = ld8(&Bs[wcol + lrow][kc * 32 + lk8]);
      bf16x8 b1 = ld8(&Bs[wcol + 16 + lrow][kc * 32 + lk8]);
      acc[0][0] = mfma16(a0, b0, acc[0][0]);
      acc[0][1] = mfma16(a0, b1, acc[0][1]);
      acc[1][0] = mfma16(a1, b0, acc[1][0]);
      acc[1][1] = mfma16(a1, b1, acc[1][1]);
    }
    __syncthreads();
  }

  #pragma unroll
  for (int mi = 0; mi < 2; ++mi)
  #pragma unroll
  for (int ni = 0; ni < 2; ++ni) {
    const int n  = nbase + wcol + ni * 16 + lrow;
    const float bn = bias[n];
    const int hh = n >> 6, hd = n & 63;
    #pragma unroll
    for (int r = 0; r < 4; ++r) {
      const int m = mbase + wrow + mi * 16 + (l >> 4) * 4 + r;
      const float v = (acc[mi][ni][r] + bn) * scale;
      const int bb = m >> 11, s = m & (SEQ - 1);
      if (mode == 0) {
        ((__bf16*)outp)[(((size_t)(bb * NH + hh) * SEQ) + s) * HDIM + hd] = (__bf16)v;
      } else if (mode == 1) {
        ((__bf16*)outp)[(((size_t)(bb * NH + hh) * HDIM) + hd) * SEQ + s] = (__bf16)v;
      } else {
        ((float*)outp)[(size_t)m * DIM + n] = v;
      }
    }
  }
}

__global__ __launch_bounds__(256, 4) void qkv_gemm(
    const float* __restrict__ x, const __bf16* __restrict__ WbT,
    const float* __restrict__ bq, const float* __restrict__ bk,
    const float* __restrict__ bv,
    __bf16* __restrict__ Qb, __bf16* __restrict__ Kb, __bf16* __restrict__ Vt) {
  const int z = blockIdx.z;
  const __bf16* Bt = WbT + (size_t)z * DIM * DIM;
  const float* bs = (z == 0) ? bq : (z == 1) ? bk : bv;
  void* o = (z == 0) ? (void*)Qb : (z == 1) ? (void*)Kb : (void*)Vt;
  const float sc = (z == 0) ? 0.125f : 1.f;  // fold 1/sqrt(HD) into Q
  gemm_tile(x, Bt, bs, o, (z == 2) ? 1 : 0, sc, blockIdx.y * 64, blockIdx.x * 64);
}

__global__ __launch_bounds__(256, 4) void out_gemm(
    const float* __restrict__ A, const __bf16* __restrict__ WbT,
    const float* __restrict__ bo, float* __restrict__ out) {
  gemm_tile(A, WbT + (size_t)3 * DIM * DIM, bo, out, 2, 1.f,
            blockIdx.y * 64, blockIdx.x * 64);
}

// ---------------------------------------------------------------------------
__global__ __launch_bounds__(256) void zero_f32(float* __restrict__ p, int n4) {
  const f32x4 zv = {0.f, 0.f, 0.f, 0.f};
  int i = blockIdx.x * 256 + threadIdx.x;
  const int stride = gridDim.x * 256;
  for (; i < n4; i += stride) ((f32x4*)p)[i] = zv;
}

// ---------------------------------------------------------------------------
// attn_sums: per-row sum of exp(score). Q pre-scaled by 1/8. k-chunked (4
// tiles), XCD-swizzled, interior fast path, dual accumulators.
// __launch_bounds__(256,4): 128 VGPR so the compiler can pipeline K loads.
// grid = 24 * 144 blocks of 256.
// ---------------------------------------------------------------------------
__global__ __launch_bounds__(256, 4) void attn_sums(
    const __bf16* __restrict__ Q, const __bf16* __restrict__ K,
    float* __restrict__ sums) {
  const int tid = threadIdx.x, l = tid & 63, w = tid >> 6;
  const int lrow = l & 15, lk8 = (l >> 4) * 8, g = l >> 4;
  const int lin = blockIdx.x;
  const int C = 144;
  const int bh = (lin & 7) * 3 + (lin >> 3) / C;
  const int cid = (lin >> 3) % C;
  int qt, t0; decode_chunk(cid, 4, qt, t0);
  const int t1 = (t0 + 4 < qt + 1) ? t0 + 4 : qt + 1;
  const int qw = qt * 64 + w * 16;
  const int qc = qw + g * 4;

  const __bf16* Qh = Q + (size_t)bh * SEQ * HDIM;
  const __bf16* Kh = K + (size_t)bh * SEQ * HDIM;
  const bf16x8 aq0 = ld8(Qh + (size_t)(qw + lrow) * HDIM + lk8);
  const bf16x8 aq1 = ld8(Qh + (size_t)(qw + lrow) * HDIM + 32 + lk8);

  f32x4 ssum = {0.f, 0.f, 0.f, 0.f};
  for (int t = t0; t < t1; ++t) {
    const int kb = t * 64;
    if (t < qt) {  // interior: no mask
      #pragma unroll
      for (int nt = 0; nt < 4; ++nt) {
        const int krow = kb + nt * 16 + lrow;
        const bf16x8 bk0 = ld8(Kh + (size_t)krow * HDIM + lk8);
        const bf16x8 bk1 = ld8(Kh + (size_t)krow * HDIM + 32 + lk8);
        f32x4 s0 = {0.f, 0.f, 0.f, 0.f}, s1 = {0.f, 0.f, 0.f, 0.f};
        s0 = mfma16(aq0, bk0, s0);
        s1 = mfma16(aq1, bk1, s1);
        #pragma unroll
        for (int r = 0; r < 4; ++r) ssum[r] += __expf(s0[r] + s1[r]);
      }
    } else {  // diagonal tile: causal mask
      #pragma unroll
      for (int nt = 0; nt < 4; ++nt) {
        const int krow = kb + nt * 16 + lrow;
        const bf16x8 bk0 = ld8(Kh + (size_t)krow * HDIM + lk8);
        const bf16x8 bk1 = ld8(Kh + (size_t)krow * HDIM + 32 + lk8);
        f32x4 s0 = {0.f, 0.f, 0.f, 0.f}, s1 = {0.f, 0.f, 0.f, 0.f};
        s0 = mfma16(aq0, bk0, s0);
        s1 = mfma16(aq1, bk1, s1);
        #pragma unroll
        for (int r = 0; r < 4; ++r)
          ssum[r] += (krow <= qc + r) ? __expf(s0[r] + s1[r]) : 0.f;
      }
    }
  }
  #pragma unroll
  for (int m = 1; m < 16; m <<= 1) {
    #pragma unroll
    for (int r = 0; r < 4; ++r) ssum[r] += __shfl_xor(ssum[r], m);
  }
  if (lrow == 0) {
    #pragma unroll
    for (int r = 0; r < 4; ++r)
      unsafeAtomicAdd(&sums[bh * SEQ + qc + r], ssum[r]);
  }
}

// ---------------------------------------------------------------------------
// attn_wpv: recompute scores, scalar Wg stores from registers (sub#2-proven),
// P staged in LDS (in-wave, NO barriers), PV -> atomicAdd into fp32 AOf.
// __launch_bounds__(256,4): 128 VGPR for load pipelining.
// k-chunked (8 tiles), XCD-swizzled. grid = 24 * 80 blocks of 256.
// ---------------------------------------------------------------------------
__global__ __launch_bounds__(256, 4) void attn_wpv(
    const __bf16* __restrict__ Q, const __bf16* __restrict__ K,
    const __bf16* __restrict__ VT, const float* __restrict__ sums,
    float* __restrict__ Wout, float* __restrict__ AOf) {
  __shared__ float Plds[4][16][68];

  const int tid = threadIdx.x, l = tid & 63, w = tid >> 6;
  const int lrow = l & 15, lk8 = (l >> 4) * 8, g = l >> 4;
  const int lin = blockIdx.x;
  const int C = 80;
  const int bh = (lin & 7) * 3 + (lin >> 3) / C;
  const int cid = (lin >> 3) % C;
  int qt, t0; decode_chunk(cid, 8, qt, t0);
  const int t1 = (t0 + 8 < qt + 1) ? t0 + 8 : qt + 1;
  const int bb = bh / NH, hh = bh % NH;
  const int qw = qt * 64 + w * 16;
  const int qc = qw + g * 4;

  const __bf16* Qh = Q + (size_t)bh * SEQ * HDIM;
  const __bf16* Kh = K + (size_t)bh * SEQ * HDIM;
  const __bf16* Vh = VT + (size_t)bh * HDIM * SEQ;
  float* Wg = Wout + (size_t)bh * SEQ * SEQ;

  const bf16x8 aq0 = ld8(Qh + (size_t)(qw + lrow) * HDIM + lk8);
  const bf16x8 aq1 = ld8(Qh + (size_t)(qw + lrow) * HDIM + 32 + lk8);

  f32x4 inv;
  #pragma unroll
  for (int r = 0; r < 4; ++r) inv[r] = 1.f / sums[bh * SEQ + qc + r];

  f32x4 acco[4] = {};
  for (int t = t0; t < t1; ++t) {
    const int kb = t * 64;
    if (t < qt) {  // interior: no mask
      #pragma unroll
      for (int nt = 0; nt < 4; ++nt) {
        const int krow = kb + nt * 16 + lrow;
        const bf16x8 bk0 = ld8(Kh + (size_t)krow * HDIM + lk8);
        const bf16x8 bk1 = ld8(Kh + (size_t)krow * HDIM + 32 + lk8);
        f32x4 s0 = {0.f, 0.f, 0.f, 0.f}, s1 = {0.f, 0.f, 0.f, 0.f};
        s0 = mfma16(aq0, bk0, s0);
        s1 = mfma16(aq1, bk1, s1);
        #pragma unroll
        for (int r = 0; r < 4; ++r) {
          const float p = __expf(s0[r] + s1[r]) * inv[r];
          Wg[(size_t)(qc + r) * SEQ + krow] = p;
          Plds[w][g * 4 + r][nt * 16 + lrow] = p;
        }
      }
    } else {  // diagonal tile: causal mask
      #pragma unroll
      for (int nt = 0; nt < 4; ++nt) {
        const int krow = kb + nt * 16 + lrow;
        const bf16x8 bk0 = ld8(Kh + (size_t)krow * HDIM + lk8);
        const bf16x8 bk1 = ld8(Kh + (size_t)krow * HDIM + 32 + lk8);
        f32x4 s0 = {0.f, 0.f, 0.f, 0.f}, s1 = {0.f, 0.f, 0.f, 0.f};
        s0 = mfma16(aq0, bk0, s0);
        s1 = mfma16(aq1, bk1, s1);
        #pragma unroll
        for (int r = 0; r < 4; ++r) {
          const float p =
              (krow <= qc + r) ? __expf(s0[r] + s1[r]) * inv[r] : 0.f;
          Wg[(size_t)(qc + r) * SEQ + krow] = p;
          Plds[w][g * 4 + r][nt * 16 + lrow] = p;
        }
      }
    }
    // PV from LDS (in-wave RAW, hardware lgkmcnt ordering; no barrier)
    #pragma unroll
    for (int kc = 0; kc < 2; ++kc) {
      const float* ps = &Plds[w][lrow][kc * 32 + lk8];
      const f32x4 p0 = *(const f32x4*)ps;
      const f32x4 p1 = *(const f32x4*)(ps + 4);
      bf16x8 aw;
      #pragma unroll
      for (int j = 0; j < 4; ++j) { aw[j] = (__bf16)p0[j]; aw[4 + j] = (__bf16)p1[j]; }
      #pragma unroll
      for (int nt = 0; nt < 4; ++nt) {
        const bf16x8 bv =
            ld8(Vh + (size_t)(nt * 16 + lrow) * SEQ + kb + kc * 32 + lk8);
        acco[nt] = mfma16(aw, bv, acco[nt]);
      }
    }
  }

  #pragma unroll
  for (int nt = 0; nt < 4; ++nt)
    #pragma unroll
    for (int r = 0; r < 4; ++r)
      unsafeAtomicAdd(
          &AOf[(size_t)(bb * SEQ + qc + r) * DIM + hh * HDIM + nt * 16 + lrow],
          acco[nt][r]);
}

// ---------------------------------------------------------------------------
// zfill: zero upper-triangle weight region. grid (8 col-chunks, 32 qt, 24 bh).
// ---------------------------------------------------------------------------
__global__ __launch_bounds__(256) void zfill(float* __restrict__ Wout) {
  const int c8 = blockIdx.x, qt = blockIdx.y, bh = blockIdx.z;
  const int kstart = (qt + 1) * 64;
  if (kstart >= SEQ) return;
  const int wseg = (SEQ - kstart) >> 3;
  const int c0 = kstart + c8 * wseg;
  const int vpr = wseg >> 2;
  float* base = Wout + (size_t)bh * SEQ * SEQ + (size_t)qt * 64 * SEQ;
  const int tid = threadIdx.x;
  const f32x4 zv = {0.f, 0.f, 0.f, 0.f};
  for (int rb = tid >> 3; rb < 64; rb += 32)
    for (int cb = tid & 7; cb < vpr; cb += 8)
      *(f32x4*)&base[(size_t)rb * SEQ + c0 + cb * 4] = zv;
}

// ---------------------------------------------------------------------------
extern "C" void kernel_launch(void* const* d_in, const int* in_sizes, int n_in,
                              void* d_out, int out_size, void* d_ws, size_t ws_size,
                              hipStream_t stream) {
  const float* x  = (const float*)d_in[0];
  const float* Wq = (const float*)d_in[2];
  const float* bq = (const float*)d_in[3];
  const float* Wk = (const float*)d_in[4];
  const float* bk = (const float*)d_in[5];
  const float* Wv = (const float*)d_in[6];
  const float* bv = (const float*)d_in[7];
  const float* Wo = (const float*)d_in[8];
  const float* bo = (const float*)d_in[9];

  char* wsb = (char*)d_ws;
  __bf16* Qb   = (__bf16*)(wsb);                 // [B,H,S,HD] bf16   6 MB
  __bf16* Kb   = (__bf16*)(wsb + 6291456);       // [B,H,S,HD] bf16   6 MB
  __bf16* Vt   = (__bf16*)(wsb + 12582912);      // [B,H,HD,S] bf16   6 MB
  float*  AOf  = (float*)(wsb + 18874368);       // [B*S, D] fp32    12 MB
  float*  sums = (float*)(wsb + 31457280);       // [24,2048] fp32  0.2 MB
  __bf16* WbT  = (__bf16*)(wsb + 31653888);      // [4,768,768] bf16 4.7 MB

  float* out   = (float*)d_out;                  // [2,2048,768] fp32
  float* attnW = out + 3145728;                  // [2,12,2048,2048] fp32

  zero_f32<<<1024, 256, 0, stream>>>(AOf, (3145728 + 49152) / 4);
  prep_wt<<<dim3(12, 12, 4), 256, 0, stream>>>(Wq, Wk, Wv, Wo, WbT);
  qkv_gemm<<<dim3(12, 64, 3), 256, 0, stream>>>(x, WbT, bq, bk, bv, Qb, Kb, Vt);
  attn_sums<<<24 * 144, 256, 0, stream>>>(Qb, Kb, sums);
  zfill<<<dim3(8, 32, 24), 256, 0, stream>>>(attnW);
  attn_wpv<<<24 * 80, 256, 0, stream>>>(Qb, Kb, Vt, sums, attnW, AOf);
  out_gemm<<<dim3(12, 64), 256, 0, stream>>>(AOf, WbT, bo, out);
}

// Round 8
// 309.127 us; speedup vs baseline: 1.3572x; 1.1300x over previous
//
#include <hip/hip_runtime.h>

#define DEV static __device__ __forceinline__

typedef __bf16 bf16x8 __attribute__((ext_vector_type(8)));
typedef float  f32x4  __attribute__((ext_vector_type(4)));

DEV bf16x8 ld8(const __bf16* p) { return *reinterpret_cast<const bf16x8*>(p); }

DEV f32x4 mfma16(bf16x8 a, bf16x8 b, f32x4 c) {
  return __builtin_amdgcn_mfma_f32_16x16x32_bf16(a, b, c, 0, 0, 0);
}

// B=2, S=2048, D=768, H=12, HD=64
#define SEQ 2048
#define DIM 768
#define NH  12
#define HDIM 64

// given chunk id cid (within one bh) and chunk size CH (in 64-k-tiles),
// find q-tile qt and first k-tile t0. lower-triangle chunks only.
DEV void decode_chunk(int cid, int CH, int& qt, int& t0) {
  int q = 0, rem = cid;
  while (true) {
    int nc = (q + CH) / CH;  // ceil((q+1)/CH)
    if (rem < nc) break;
    rem -= nc; ++q;
  }
  qt = q; t0 = rem * CH;
}

// ---------------------------------------------------------------------------
// prep_wt: transpose+convert the 4 weight matrices to bf16 [out_n][in_k].
// ---------------------------------------------------------------------------
__global__ __launch_bounds__(256) void prep_wt(
    const float* __restrict__ Wq, const float* __restrict__ Wk,
    const float* __restrict__ Wv, const float* __restrict__ Wo,
    __bf16* __restrict__ WbT) {
  __shared__ float T[64][65];
  const int z = blockIdx.z;
  const float* W = (z == 0) ? Wq : (z == 1) ? Wk : (z == 2) ? Wv : Wo;
  const int kb = blockIdx.x * 64, nb = blockIdx.y * 64;
  const int t = threadIdx.x, r = t >> 2, c4 = (t & 3) * 16;
  #pragma unroll
  for (int j = 0; j < 16; j += 4) {
    f32x4 v = *(const f32x4*)(W + (size_t)(kb + r) * DIM + nb + c4 + j);
    T[r][c4 + j]     = v[0]; T[r][c4 + j + 1] = v[1];
    T[r][c4 + j + 2] = v[2]; T[r][c4 + j + 3] = v[3];
  }
  __syncthreads();
  bf16x8 o0, o1;
  #pragma unroll
  for (int j = 0; j < 8; ++j) {
    o0[j] = (__bf16)T[c4 + j][r];
    o1[j] = (__bf16)T[c4 + 8 + j][r];
  }
  __bf16* dst = WbT + (size_t)z * DIM * DIM + (size_t)(nb + r) * DIM + kb + c4;
  *(bf16x8*)dst = o0;
  *(bf16x8*)(dst + 8) = o1;
}

// ---------------------------------------------------------------------------
// shared GEMM tile body: A fp32, B pre-transposed bf16 [n][k].
// ---------------------------------------------------------------------------
DEV void gemm_tile(const float* __restrict__ Af, const __bf16* __restrict__ Bt,
                   const float* __restrict__ bias, void* __restrict__ outp,
                   const int mode, const float scale,
                   const int mbase, const int nbase) {
  __shared__ __bf16 As[64][72];
  __shared__ __bf16 Bs[64][72];

  const int tid  = threadIdx.x;
  const int l    = tid & 63;
  const int w    = tid >> 6;
  const int lrow = l & 15;
  const int lk8  = (l >> 4) * 8;
  const int wrow = (w >> 1) * 32, wcol = (w & 1) * 32;

  f32x4 acc[2][2] = {};

  const int arow = tid >> 2;
  const int acol = (tid & 3) * 16;

  for (int kk = 0; kk < DIM; kk += 64) {
    {
      const float* src = Af + (size_t)(mbase + arow) * DIM + kk + acol;
      f32x4 f0 = *(const f32x4*)(src);
      f32x4 f1 = *(const f32x4*)(src + 4);
      f32x4 f2 = *(const f32x4*)(src + 8);
      f32x4 f3 = *(const f32x4*)(src + 12);
      bf16x8 v0, v1;
      #pragma unroll
      for (int j = 0; j < 4; ++j) {
        v0[j] = (__bf16)f0[j]; v0[4 + j] = (__bf16)f1[j];
        v1[j] = (__bf16)f2[j]; v1[4 + j] = (__bf16)f3[j];
      }
      *(bf16x8*)&As[arow][acol]     = v0;
      *(bf16x8*)&As[arow][acol + 8] = v1;
    }
    {
      const __bf16* bsrc = Bt + (size_t)(nbase + arow) * DIM + kk + acol;
      *(bf16x8*)&Bs[arow][acol]     = ld8(bsrc);
      *(bf16x8*)&Bs[arow][acol + 8] = ld8(bsrc + 8);
    }
    __syncthreads();
    #pragma unroll
    for (int kc = 0; kc < 2; ++kc) {
      bf16x8 a0 = ld8(&As[wrow + lrow][kc * 32 + lk8]);
      bf16x8 a1 = ld8(&As[wrow + 16 + lrow][kc * 32 + lk8]);
      bf16x8 b0 = ld8(&Bs[wcol + lrow][kc * 32 + lk8]);
      bf16x8 b1 = ld8(&Bs[wcol + 16 + lrow][kc * 32 + lk8]);
      acc[0][0] = mfma16(a0, b0, acc[0][0]);
      acc[0][1] = mfma16(a0, b1, acc[0][1]);
      acc[1][0] = mfma16(a1, b0, acc[1][0]);
      acc[1][1] = mfma16(a1, b1, acc[1][1]);
    }
    __syncthreads();
  }

  #pragma unroll
  for (int mi = 0; mi < 2; ++mi)
  #pragma unroll
  for (int ni = 0; ni < 2; ++ni) {
    const int n  = nbase + wcol + ni * 16 + lrow;
    const float bn = bias[n];
    const int hh = n >> 6, hd = n & 63;
    #pragma unroll
    for (int r = 0; r < 4; ++r) {
      const int m = mbase + wrow + mi * 16 + (l >> 4) * 4 + r;
      const float v = (acc[mi][ni][r] + bn) * scale;
      const int bb = m >> 11, s = m & (SEQ - 1);
      if (mode == 0) {
        ((__bf16*)outp)[(((size_t)(bb * NH + hh) * SEQ) + s) * HDIM + hd] = (__bf16)v;
      } else if (mode == 1) {
        ((__bf16*)outp)[(((size_t)(bb * NH + hh) * HDIM) + hd) * SEQ + s] = (__bf16)v;
      } else {
        ((float*)outp)[(size_t)m * DIM + n] = v;
      }
    }
  }
}

__global__ __launch_bounds__(256, 4) void qkv_gemm(
    const float* __restrict__ x, const __bf16* __restrict__ WbT,
    const float* __restrict__ bq, const float* __restrict__ bk,
    const float* __restrict__ bv,
    __bf16* __restrict__ Qb, __bf16* __restrict__ Kb, __bf16* __restrict__ Vt) {
  const int z = blockIdx.z;
  const __bf16* Bt = WbT + (size_t)z * DIM * DIM;
  const float* bs = (z == 0) ? bq : (z == 1) ? bk : bv;
  void* o = (z == 0) ? (void*)Qb : (z == 1) ? (void*)Kb : (void*)Vt;
  const float sc = (z == 0) ? 0.125f : 1.f;  // fold 1/sqrt(HD) into Q
  gemm_tile(x, Bt, bs, o, (z == 2) ? 1 : 0, sc, blockIdx.y * 64, blockIdx.x * 64);
}

__global__ __launch_bounds__(256, 4) void out_gemm(
    const float* __restrict__ A, const __bf16* __restrict__ WbT,
    const float* __restrict__ bo, float* __restrict__ out) {
  gemm_tile(A, WbT + (size_t)3 * DIM * DIM, bo, out, 2, 1.f,
            blockIdx.y * 64, blockIdx.x * 64);
}

// ---------------------------------------------------------------------------
__global__ __launch_bounds__(256) void zero_f32(float* __restrict__ p, int n4) {
  const f32x4 zv = {0.f, 0.f, 0.f, 0.f};
  int i = blockIdx.x * 256 + threadIdx.x;
  const int stride = gridDim.x * 256;
  for (; i < n4; i += stride) ((f32x4*)p)[i] = zv;
}

// ---------------------------------------------------------------------------
// attn_sums: swapped-operand QK^T (S^T frags: lane owns q=lrow, k=g*4+r),
// per-lane partial sums + 2 shuffles + one atomic per lane (R6-proven).
// FUSED upper-triangle zero-fill: each chunk zeroes its reflected tiles
// (t, qt) for t in [t0, min(t1,qt)) -- exact partition of the strict upper
// triangle; diagonal tile written (with zeros) by attn_wpv.
// grid = 24 * 144 blocks of 256.
// ---------------------------------------------------------------------------
__global__ __launch_bounds__(256, 4) void attn_sums(
    const __bf16* __restrict__ Q, const __bf16* __restrict__ K,
    float* __restrict__ sums, float* __restrict__ Wout) {
  const int tid = threadIdx.x, l = tid & 63, w = tid >> 6;
  const int lrow = l & 15, lk8 = (l >> 4) * 8, g = l >> 4;
  const int lin = blockIdx.x;
  const int C = 144;
  const int bh = (lin & 7) * 3 + (lin >> 3) / C;
  const int cid = (lin >> 3) % C;
  int qt, t0; decode_chunk(cid, 4, qt, t0);
  const int t1 = (t0 + 4 < qt + 1) ? t0 + 4 : qt + 1;
  const int qw = qt * 64 + w * 16;
  const int q  = qw + lrow;   // lane's q row (S^T layout)

  const __bf16* Qh = Q + (size_t)bh * SEQ * HDIM;
  const __bf16* Kh = K + (size_t)bh * SEQ * HDIM;
  const bf16x8 bq0 = ld8(Qh + (size_t)q * HDIM + lk8);        // B operand (Q)
  const bf16x8 bq1 = ld8(Qh + (size_t)q * HDIM + 32 + lk8);

  float ssum = 0.f;
  for (int t = t0; t < t1; ++t) {
    const int kb = t * 64;
    #pragma unroll
    for (int nt = 0; nt < 4; ++nt) {
      const int krow = kb + nt * 16 + lrow;                   // A operand (K)
      const bf16x8 ak0 = ld8(Kh + (size_t)krow * HDIM + lk8);
      const bf16x8 ak1 = ld8(Kh + (size_t)krow * HDIM + 32 + lk8);
      f32x4 s0 = {0.f, 0.f, 0.f, 0.f}, s1 = {0.f, 0.f, 0.f, 0.f};
      s0 = mfma16(ak0, bq0, s0);
      s1 = mfma16(ak1, bq1, s1);
      const int k0 = kb + nt * 16 + g * 4;                    // lane's k base
      if (t < qt || k0 + 3 <= q) {  // fully unmasked
        #pragma unroll
        for (int r = 0; r < 4; ++r) ssum += __expf(s0[r] + s1[r]);
      } else {
        #pragma unroll
        for (int r = 0; r < 4; ++r)
          ssum += (k0 + r <= q) ? __expf(s0[r] + s1[r]) : 0.f;
      }
    }
  }
  ssum += __shfl_xor(ssum, 16);
  ssum += __shfl_xor(ssum, 32);
  if (g == 0) unsafeAtomicAdd(&sums[bh * SEQ + q], ssum);

  // ---- fused zero-fill of reflected upper-triangle tiles ----
  const int tz = (t1 < qt) ? t1 : qt;
  if (t0 < tz) {
    float* Wg = Wout + (size_t)bh * SEQ * SEQ;
    const int zr = tid >> 2;             // 0..63
    const int zc = (tid & 3) * 4;        // 0,4,8,12
    const f32x4 zv = {0.f, 0.f, 0.f, 0.f};
    for (int t = t0; t < tz; ++t) {
      float* base = Wg + (size_t)(t * 64 + zr) * SEQ + qt * 64 + zc;
      #pragma unroll
      for (int c = 0; c < 4; ++c) *(f32x4*)(base + c * 16) = zv;
    }
  }
}

// ---------------------------------------------------------------------------
// attn_wpv: swapped-operand QK^T -> S^T frags; f32x4 Wg stores DIRECT from
// registers (R6-proven mapping); P staged to LDS via ds_write_b128 (f32);
// PV reads P from LDS (R3/R7-proven in-wave pattern, no barriers) ->
// full-width mfma16 against V^T; atomicAdd into fp32 AOf.
// k-chunked (8 tiles), XCD-swizzled. grid = 24 * 80 blocks of 256.
// ---------------------------------------------------------------------------
__global__ __launch_bounds__(256, 4) void attn_wpv(
    const __bf16* __restrict__ Q, const __bf16* __restrict__ K,
    const __bf16* __restrict__ VT, const float* __restrict__ sums,
    float* __restrict__ Wout, float* __restrict__ AOf) {
  __shared__ float Plds[4][16][68];

  const int tid = threadIdx.x, l = tid & 63, w = tid >> 6;
  const int lrow = l & 15, lk8 = (l >> 4) * 8, g = l >> 4;
  const int lin = blockIdx.x;
  const int C = 80;
  const int bh = (lin & 7) * 3 + (lin >> 3) / C;
  const int cid = (lin >> 3) % C;
  int qt, t0; decode_chunk(cid, 8, qt, t0);
  const int t1 = (t0 + 8 < qt + 1) ? t0 + 8 : qt + 1;
  const int bb = bh / NH, hh = bh % NH;
  const int qw = qt * 64 + w * 16;
  const int q  = qw + lrow;   // lane's q row (S^T layout)

  const __bf16* Qh = Q + (size_t)bh * SEQ * HDIM;
  const __bf16* Kh = K + (size_t)bh * SEQ * HDIM;
  const __bf16* Vh = VT + (size_t)bh * HDIM * SEQ;
  float* Wg = Wout + (size_t)bh * SEQ * SEQ;

  const bf16x8 bq0 = ld8(Qh + (size_t)q * HDIM + lk8);
  const bf16x8 bq1 = ld8(Qh + (size_t)q * HDIM + 32 + lk8);
  const float inv = 1.f / sums[bh * SEQ + q];

  f32x4 acco[4] = {};
  for (int t = t0; t < t1; ++t) {
    const int kb = t * 64;
    #pragma unroll
    for (int nt = 0; nt < 4; ++nt) {
      const int krow = kb + nt * 16 + lrow;
      const bf16x8 ak0 = ld8(Kh + (size_t)krow * HDIM + lk8);
      const bf16x8 ak1 = ld8(Kh + (size_t)krow * HDIM + 32 + lk8);
      f32x4 s0 = {0.f, 0.f, 0.f, 0.f}, s1 = {0.f, 0.f, 0.f, 0.f};
      s0 = mfma16(ak0, bq0, s0);
      s1 = mfma16(ak1, bq1, s1);
      const int k0 = kb + nt * 16 + g * 4;
      f32x4 pv;
      if (t < qt || k0 + 3 <= q) {
        #pragma unroll
        for (int r = 0; r < 4; ++r) pv[r] = __expf(s0[r] + s1[r]) * inv;
      } else {
        #pragma unroll
        for (int r = 0; r < 4; ++r)
          pv[r] = (k0 + r <= q) ? __expf(s0[r] + s1[r]) * inv : 0.f;
      }
      // direct vectorized weight store: lane owns Wg[q][k0..k0+3]
      *(f32x4*)&Wg[(size_t)q * SEQ + k0] = pv;
      // P staging: one ds_write_b128 (row q=lrow, cols nt*16+g*4..+3)
      *(f32x4*)&Plds[w][lrow][nt * 16 + g * 4] = pv;
    }
    // PV from LDS (in-wave RAW, hardware lgkmcnt ordering; no barrier)
    #pragma unroll
    for (int kc = 0; kc < 2; ++kc) {
      const float* ps = &Plds[w][lrow][kc * 32 + lk8];
      const f32x4 p0 = *(const f32x4*)ps;
      const f32x4 p1 = *(const f32x4*)(ps + 4);
      bf16x8 aw;
      #pragma unroll
      for (int j = 0; j < 4; ++j) { aw[j] = (__bf16)p0[j]; aw[4 + j] = (__bf16)p1[j]; }
      #pragma unroll
      for (int nt = 0; nt < 4; ++nt) {
        const bf16x8 bv =
            ld8(Vh + (size_t)(nt * 16 + lrow) * SEQ + kb + kc * 32 + lk8);
        acco[nt] = mfma16(aw, bv, acco[nt]);
      }
    }
  }

  #pragma unroll
  for (int nt = 0; nt < 4; ++nt)
    #pragma unroll
    for (int r = 0; r < 4; ++r)
      unsafeAtomicAdd(
          &AOf[(size_t)(bb * SEQ + qw + g * 4 + r) * DIM + hh * HDIM + nt * 16 + lrow],
          acco[nt][r]);
}

// ---------------------------------------------------------------------------
extern "C" void kernel_launch(void* const* d_in, const int* in_sizes, int n_in,
                              void* d_out, int out_size, void* d_ws, size_t ws_size,
                              hipStream_t stream) {
  const float* x  = (const float*)d_in[0];
  const float* Wq = (const float*)d_in[2];
  const float* bq = (const float*)d_in[3];
  const float* Wk = (const float*)d_in[4];
  const float* bk = (const float*)d_in[5];
  const float* Wv = (const float*)d_in[6];
  const float* bv = (const float*)d_in[7];
  const float* Wo = (const float*)d_in[8];
  const float* bo = (const float*)d_in[9];

  char* wsb = (char*)d_ws;
  __bf16* Qb   = (__bf16*)(wsb);                 // [B,H,S,HD] bf16   6 MB
  __bf16* Kb   = (__bf16*)(wsb + 6291456);       // [B,H,S,HD] bf16   6 MB
  __bf16* Vt   = (__bf16*)(wsb + 12582912);      // [B,H,HD,S] bf16   6 MB
  float*  AOf  = (float*)(wsb + 18874368);       // [B*S, D] fp32    12 MB
  float*  sums = (float*)(wsb + 31457280);       // [24,2048] fp32  0.2 MB
  __bf16* WbT  = (__bf16*)(wsb + 31653888);      // [4,768,768] bf16 4.7 MB

  float* out   = (float*)d_out;                  // [2,2048,768] fp32
  float* attnW = out + 3145728;                  // [2,12,2048,2048] fp32

  zero_f32<<<1024, 256, 0, stream>>>(AOf, (3145728 + 49152) / 4);
  prep_wt<<<dim3(12, 12, 4), 256, 0, stream>>>(Wq, Wk, Wv, Wo, WbT);
  qkv_gemm<<<dim3(12, 64, 3), 256, 0, stream>>>(x, WbT, bq, bk, bv, Qb, Kb, Vt);
  attn_sums<<<24 * 144, 256, 0, stream>>>(Qb, Kb, sums, attnW);
  attn_wpv<<<24 * 80, 256, 0, stream>>>(Qb, Kb, Vt, sums, attnW, AOf);
  out_gemm<<<dim3(12, 64), 256, 0, stream>>>(AOf, WbT, bo, out);
}

// Round 9
// 279.783 us; speedup vs baseline: 1.4995x; 1.1049x over previous
//
#include <hip/hip_runtime.h>

#define DEV static __device__ __forceinline__

typedef __bf16 bf16x8 __attribute__((ext_vector_type(8)));
typedef float  f32x4  __attribute__((ext_vector_type(4)));

DEV bf16x8 ld8(const __bf16* p) { return *reinterpret_cast<const bf16x8*>(p); }

DEV f32x4 mfma16(bf16x8 a, bf16x8 b, f32x4 c) {
  return __builtin_amdgcn_mfma_f32_16x16x32_bf16(a, b, c, 0, 0, 0);
}

// B=2, S=2048, D=768, H=12, HD=64
#define SEQ 2048
#define DIM 768
#define NH  12
#define HDIM 64

// chunk decode for 128-row q-tiles: q-tile qt has 2*qt+2 k-tiles (64 cols).
DEV void decode_chunk2(int cid, int CH, int& qt, int& t0) {
  int q = 0, rem = cid;
  while (true) {
    int nc = (2 * q + 2 + CH - 1) / CH;
    if (rem < nc) break;
    rem -= nc; ++q;
  }
  qt = q; t0 = rem * CH;
}

// ---------------------------------------------------------------------------
// cvt_x: x fp32 -> bf16. grid 1536 x 256, 8 elems/thread.
// ---------------------------------------------------------------------------
__global__ __launch_bounds__(256) void cvt_x(const float* __restrict__ x,
                                             __bf16* __restrict__ xb) {
  const int i = (blockIdx.x * 256 + threadIdx.x) * 8;
  f32x4 a = *(const f32x4*)(x + i);
  f32x4 b = *(const f32x4*)(x + i + 4);
  bf16x8 v;
  #pragma unroll
  for (int j = 0; j < 4; ++j) { v[j] = (__bf16)a[j]; v[4 + j] = (__bf16)b[j]; }
  *(bf16x8*)(xb + i) = v;
}

// ---------------------------------------------------------------------------
// prep_wt: transpose+convert the 4 weight matrices to bf16 [out_n][in_k].
// ---------------------------------------------------------------------------
__global__ __launch_bounds__(256) void prep_wt(
    const float* __restrict__ Wq, const float* __restrict__ Wk,
    const float* __restrict__ Wv, const float* __restrict__ Wo,
    __bf16* __restrict__ WbT) {
  __shared__ float T[64][65];
  const int z = blockIdx.z;
  const float* W = (z == 0) ? Wq : (z == 1) ? Wk : (z == 2) ? Wv : Wo;
  const int kb = blockIdx.x * 64, nb = blockIdx.y * 64;
  const int t = threadIdx.x, r = t >> 2, c4 = (t & 3) * 16;
  #pragma unroll
  for (int j = 0; j < 16; j += 4) {
    f32x4 v = *(const f32x4*)(W + (size_t)(kb + r) * DIM + nb + c4 + j);
    T[r][c4 + j]     = v[0]; T[r][c4 + j + 1] = v[1];
    T[r][c4 + j + 2] = v[2]; T[r][c4 + j + 3] = v[3];
  }
  __syncthreads();
  bf16x8 o0, o1;
  #pragma unroll
  for (int j = 0; j < 8; ++j) {
    o0[j] = (__bf16)T[c4 + j][r];
    o1[j] = (__bf16)T[c4 + 8 + j][r];
  }
  __bf16* dst = WbT + (size_t)z * DIM * DIM + (size_t)(nb + r) * DIM + kb + c4;
  *(bf16x8*)dst = o0;
  *(bf16x8*)(dst + 8) = o1;
}

// ---------------------------------------------------------------------------
// shared GEMM tile body: A fp32 (Af) or bf16 (Ab); B pre-transposed bf16.
// ---------------------------------------------------------------------------
DEV void gemm_tile(const float* __restrict__ Af, const __bf16* __restrict__ Ab,
                   const __bf16* __restrict__ Bt,
                   const float* __restrict__ bias, void* __restrict__ outp,
                   const int mode, const float scale,
                   const int mbase, const int nbase) {
  __shared__ __bf16 As[64][72];
  __shared__ __bf16 Bs[64][72];

  const int tid  = threadIdx.x;
  const int l    = tid & 63;
  const int w    = tid >> 6;
  const int lrow = l & 15;
  const int lk8  = (l >> 4) * 8;
  const int wrow = (w >> 1) * 32, wcol = (w & 1) * 32;

  f32x4 acc[2][2] = {};

  const int arow = tid >> 2;
  const int acol = (tid & 3) * 16;

  for (int kk = 0; kk < DIM; kk += 64) {
    if (Ab) {
      const __bf16* asrc = Ab + (size_t)(mbase + arow) * DIM + kk + acol;
      *(bf16x8*)&As[arow][acol]     = ld8(asrc);
      *(bf16x8*)&As[arow][acol + 8] = ld8(asrc + 8);
    } else {
      const float* src = Af + (size_t)(mbase + arow) * DIM + kk + acol;
      f32x4 f0 = *(const f32x4*)(src);
      f32x4 f1 = *(const f32x4*)(src + 4);
      f32x4 f2 = *(const f32x4*)(src + 8);
      f32x4 f3 = *(const f32x4*)(src + 12);
      bf16x8 v0, v1;
      #pragma unroll
      for (int j = 0; j < 4; ++j) {
        v0[j] = (__bf16)f0[j]; v0[4 + j] = (__bf16)f1[j];
        v1[j] = (__bf16)f2[j]; v1[4 + j] = (__bf16)f3[j];
      }
      *(bf16x8*)&As[arow][acol]     = v0;
      *(bf16x8*)&As[arow][acol + 8] = v1;
    }
    {
      const __bf16* bsrc = Bt + (size_t)(nbase + arow) * DIM + kk + acol;
      *(bf16x8*)&Bs[arow][acol]     = ld8(bsrc);
      *(bf16x8*)&Bs[arow][acol + 8] = ld8(bsrc + 8);
    }
    __syncthreads();
    #pragma unroll
    for (int kc = 0; kc < 2; ++kc) {
      bf16x8 a0 = ld8(&As[wrow + lrow][kc * 32 + lk8]);
      bf16x8 a1 = ld8(&As[wrow + 16 + lrow][kc * 32 + lk8]);
      bf16x8 b0 = ld8(&Bs[wcol + lrow][kc * 32 + lk8]);
      bf16x8 b1 = ld8(&Bs[wcol + 16 + lrow][kc * 32 + lk8]);
      acc[0][0] = mfma16(a0, b0, acc[0][0]);
      acc[0][1] = mfma16(a0, b1, acc[0][1]);
      acc[1][0] = mfma16(a1, b0, acc[1][0]);
      acc[1][1] = mfma16(a1, b1, acc[1][1]);
    }
    __syncthreads();
  }

  #pragma unroll
  for (int mi = 0; mi < 2; ++mi)
  #pragma unroll
  for (int ni = 0; ni < 2; ++ni) {
    const int n  = nbase + wcol + ni * 16 + lrow;
    const float bn = bias[n];
    const int hh = n >> 6, hd = n & 63;
    #pragma unroll
    for (int r = 0; r < 4; ++r) {
      const int m = mbase + wrow + mi * 16 + (l >> 4) * 4 + r;
      const float v = (acc[mi][ni][r] + bn) * scale;
      const int bb = m >> 11, s = m & (SEQ - 1);
      if (mode == 0) {
        ((__bf16*)outp)[(((size_t)(bb * NH + hh) * SEQ) + s) * HDIM + hd] = (__bf16)v;
      } else if (mode == 1) {
        ((__bf16*)outp)[(((size_t)(bb * NH + hh) * HDIM) + hd) * SEQ + s] = (__bf16)v;
      } else {
        ((float*)outp)[(size_t)m * DIM + n] = v;
      }
    }
  }
}

__global__ __launch_bounds__(256, 4) void qkv_gemm(
    const __bf16* __restrict__ xb, const __bf16* __restrict__ WbT,
    const float* __restrict__ bq, const float* __restrict__ bk,
    const float* __restrict__ bv,
    __bf16* __restrict__ Qb, __bf16* __restrict__ Kb, __bf16* __restrict__ Vt) {
  const int z = blockIdx.z;
  const __bf16* Bt = WbT + (size_t)z * DIM * DIM;
  const float* bs = (z == 0) ? bq : (z == 1) ? bk : bv;
  void* o = (z == 0) ? (void*)Qb : (z == 1) ? (void*)Kb : (void*)Vt;
  const float sc = (z == 0) ? 0.125f : 1.f;  // fold 1/sqrt(HD) into Q
  gemm_tile(nullptr, xb, Bt, bs, o, (z == 2) ? 1 : 0, sc,
            blockIdx.y * 64, blockIdx.x * 64);
}

__global__ __launch_bounds__(256, 4) void out_gemm(
    const float* __restrict__ A, const __bf16* __restrict__ WbT,
    const float* __restrict__ bo, float* __restrict__ out) {
  gemm_tile(A, nullptr, WbT + (size_t)3 * DIM * DIM, bo, out, 2, 1.f,
            blockIdx.y * 64, blockIdx.x * 64);
}

// ---------------------------------------------------------------------------
__global__ __launch_bounds__(256) void zero_f32(float* __restrict__ p, int n4) {
  const f32x4 zv = {0.f, 0.f, 0.f, 0.f};
  int i = blockIdx.x * 256 + threadIdx.x;
  const int stride = gridDim.x * 256;
  for (; i < n4; i += stride) ((f32x4*)p)[i] = zv;
}

// ---------------------------------------------------------------------------
// attn_sums: swapped-operand QK^T, 2 q-frags/wave (block = 128 q rows) so
// each K-tile load serves 4 MFMAs. Per-lane partial sums + 2 shuffles +
// atomic (R6/R8-proven). Fused reflected upper-triangle zero-fill.
// grid = 8 * 3 * 72 = 1728 blocks of 256.
// ---------------------------------------------------------------------------
__global__ __launch_bounds__(256, 4) void attn_sums(
    const __bf16* __restrict__ Q, const __bf16* __restrict__ K,
    float* __restrict__ sums, float* __restrict__ Wout) {
  const int tid = threadIdx.x, l = tid & 63, w = tid >> 6;
  const int lrow = l & 15, lk8 = (l >> 4) * 8, g = l >> 4;
  const int lin = blockIdx.x;
  const int C = 72;
  const int bh = (lin & 7) * 3 + (lin >> 3) / C;
  const int cid = (lin >> 3) % C;
  int qt, t0; decode_chunk2(cid, 4, qt, t0);
  const int tmax = 2 * qt + 2;
  const int t1 = (t0 + 4 < tmax) ? t0 + 4 : tmax;
  const int fb0 = qt * 128 + w * 32;   // frag A q-base
  const int fb1 = fb0 + 16;            // frag B q-base
  const int q0 = fb0 + lrow, q1 = fb1 + lrow;

  const __bf16* Qh = Q + (size_t)bh * SEQ * HDIM;
  const __bf16* Kh = K + (size_t)bh * SEQ * HDIM;
  const bf16x8 bqA0 = ld8(Qh + (size_t)q0 * HDIM + lk8);
  const bf16x8 bqA1 = ld8(Qh + (size_t)q0 * HDIM + 32 + lk8);
  const bf16x8 bqB0 = ld8(Qh + (size_t)q1 * HDIM + lk8);
  const bf16x8 bqB1 = ld8(Qh + (size_t)q1 * HDIM + 32 + lk8);

  float sA = 0.f, sB = 0.f;
  for (int t = t0; t < t1; ++t) {
    const int kb = t * 64;
    const bool liveA = (kb <= fb0 + 15);
    const bool liveB = (kb <= fb1 + 15);   // liveA implies liveB
    if (!liveB) continue;                  // whole tile above both frags
    #pragma unroll
    for (int nt = 0; nt < 4; ++nt) {
      const int krow = kb + nt * 16 + lrow;
      const bf16x8 ak0 = ld8(Kh + (size_t)krow * HDIM + lk8);
      const bf16x8 ak1 = ld8(Kh + (size_t)krow * HDIM + 32 + lk8);
      const int k0 = kb + nt * 16 + g * 4;
      if (liveA) {
        f32x4 s0 = {0.f, 0.f, 0.f, 0.f}, s1 = {0.f, 0.f, 0.f, 0.f};
        s0 = mfma16(ak0, bqA0, s0);
        s1 = mfma16(ak1, bqA1, s1);
        if (kb + 63 <= fb0) {
          #pragma unroll
          for (int r = 0; r < 4; ++r) sA += __expf(s0[r] + s1[r]);
        } else {
          #pragma unroll
          for (int r = 0; r < 4; ++r)
            sA += (k0 + r <= q0) ? __expf(s0[r] + s1[r]) : 0.f;
        }
      }
      {
        f32x4 s0 = {0.f, 0.f, 0.f, 0.f}, s1 = {0.f, 0.f, 0.f, 0.f};
        s0 = mfma16(ak0, bqB0, s0);
        s1 = mfma16(ak1, bqB1, s1);
        if (kb + 63 <= fb1) {
          #pragma unroll
          for (int r = 0; r < 4; ++r) sB += __expf(s0[r] + s1[r]);
        } else {
          #pragma unroll
          for (int r = 0; r < 4; ++r)
            sB += (k0 + r <= q1) ? __expf(s0[r] + s1[r]) : 0.f;
        }
      }
    }
  }
  sA += __shfl_xor(sA, 16); sA += __shfl_xor(sA, 32);
  sB += __shfl_xor(sB, 16); sB += __shfl_xor(sB, 32);
  if (g == 0) {
    unsafeAtomicAdd(&sums[bh * SEQ + q0], sA);
    unsafeAtomicAdd(&sums[bh * SEQ + q1], sB);
  }

  // ---- fused zero-fill: reflected tiles t in [t0, min(t1, 2*qt)) ----
  const int tz = (t1 < 2 * qt) ? t1 : 2 * qt;
  if (t0 < tz) {
    float* Wg = Wout + (size_t)bh * SEQ * SEQ;
    const int zr = tid >> 2;
    const int zc = (tid & 3) * 32;
    const f32x4 zv = {0.f, 0.f, 0.f, 0.f};
    for (int t = t0; t < tz; ++t) {
      float* base = Wg + (size_t)(t * 64 + zr) * SEQ + qt * 128 + zc;
      #pragma unroll
      for (int c = 0; c < 8; ++c) *(f32x4*)(base + c * 4) = zv;
    }
  }
}

// ---------------------------------------------------------------------------
// attn_wpv: swapped-operand QK^T, 2 q-frags/wave; f32x4 Wg stores direct from
// registers; P via ds_write_b128 -> LDS (in-wave RAW, no barriers) -> PV
// full-width mfma against V^T (V loads shared across frags); atomicAdd AOf.
// grid = 8 * 3 * 40 = 960 blocks of 256.
// ---------------------------------------------------------------------------
__global__ __launch_bounds__(256, 4) void attn_wpv(
    const __bf16* __restrict__ Q, const __bf16* __restrict__ K,
    const __bf16* __restrict__ VT, const float* __restrict__ sums,
    float* __restrict__ Wout, float* __restrict__ AOf) {
  __shared__ float Plds[4][2][16][68];

  const int tid = threadIdx.x, l = tid & 63, w = tid >> 6;
  const int lrow = l & 15, lk8 = (l >> 4) * 8, g = l >> 4;
  const int lin = blockIdx.x;
  const int C = 40;
  const int bh = (lin & 7) * 3 + (lin >> 3) / C;
  const int cid = (lin >> 3) % C;
  int qt, t0; decode_chunk2(cid, 8, qt, t0);
  const int tmax = 2 * qt + 2;
  const int t1 = (t0 + 8 < tmax) ? t0 + 8 : tmax;
  const int bb = bh / NH, hh = bh % NH;
  const int fb0 = qt * 128 + w * 32;
  const int fb1 = fb0 + 16;
  const int q0 = fb0 + lrow, q1 = fb1 + lrow;

  const __bf16* Qh = Q + (size_t)bh * SEQ * HDIM;
  const __bf16* Kh = K + (size_t)bh * SEQ * HDIM;
  const __bf16* Vh = VT + (size_t)bh * HDIM * SEQ;
  float* Wg = Wout + (size_t)bh * SEQ * SEQ;

  const bf16x8 bqA0 = ld8(Qh + (size_t)q0 * HDIM + lk8);
  const bf16x8 bqA1 = ld8(Qh + (size_t)q0 * HDIM + 32 + lk8);
  const bf16x8 bqB0 = ld8(Qh + (size_t)q1 * HDIM + lk8);
  const bf16x8 bqB1 = ld8(Qh + (size_t)q1 * HDIM + 32 + lk8);
  const float invA = 1.f / sums[bh * SEQ + q0];
  const float invB = 1.f / sums[bh * SEQ + q1];

  f32x4 accA[4] = {}, accB[4] = {};
  for (int t = t0; t < t1; ++t) {
    const int kb = t * 64;
    const bool liveA = (kb <= fb0 + 15);
    const bool liveB = (kb <= fb1 + 15);
    const f32x4 zv = {0.f, 0.f, 0.f, 0.f};
    if (!liveB) {
      // tile fully above both frags: mandatory zero weights, no compute
      #pragma unroll
      for (int nt = 0; nt < 4; ++nt) {
        const int k0 = kb + nt * 16 + g * 4;
        *(f32x4*)&Wg[(size_t)q0 * SEQ + k0] = zv;
        *(f32x4*)&Wg[(size_t)q1 * SEQ + k0] = zv;
      }
      continue;
    }
    #pragma unroll
    for (int nt = 0; nt < 4; ++nt) {
      const int krow = kb + nt * 16 + lrow;
      const bf16x8 ak0 = ld8(Kh + (size_t)krow * HDIM + lk8);
      const bf16x8 ak1 = ld8(Kh + (size_t)krow * HDIM + 32 + lk8);
      const int k0 = kb + nt * 16 + g * 4;
      // frag A
      f32x4 pvA = zv;
      if (liveA) {
        f32x4 s0 = {0.f, 0.f, 0.f, 0.f}, s1 = {0.f, 0.f, 0.f, 0.f};
        s0 = mfma16(ak0, bqA0, s0);
        s1 = mfma16(ak1, bqA1, s1);
        if (kb + 63 <= fb0) {
          #pragma unroll
          for (int r = 0; r < 4; ++r) pvA[r] = __expf(s0[r] + s1[r]) * invA;
        } else {
          #pragma unroll
          for (int r = 0; r < 4; ++r)
            pvA[r] = (k0 + r <= q0) ? __expf(s0[r] + s1[r]) * invA : 0.f;
        }
        *(f32x4*)&Plds[w][0][lrow][nt * 16 + g * 4] = pvA;
      }
      *(f32x4*)&Wg[(size_t)q0 * SEQ + k0] = pvA;
      // frag B
      f32x4 pvB;
      {
        f32x4 s0 = {0.f, 0.f, 0.f, 0.f}, s1 = {0.f, 0.f, 0.f, 0.f};
        s0 = mfma16(ak0, bqB0, s0);
        s1 = mfma16(ak1, bqB1, s1);
        if (kb + 63 <= fb1) {
          #pragma unroll
          for (int r = 0; r < 4; ++r) pvB[r] = __expf(s0[r] + s1[r]) * invB;
        } else {
          #pragma unroll
          for (int r = 0; r < 4; ++r)
            pvB[r] = (k0 + r <= q1) ? __expf(s0[r] + s1[r]) * invB : 0.f;
        }
      }
      *(f32x4*)&Wg[(size_t)q1 * SEQ + k0] = pvB;
      *(f32x4*)&Plds[w][1][lrow][nt * 16 + g * 4] = pvB;
    }
    // PV from LDS (in-wave RAW, hardware lgkmcnt ordering; no barrier)
    #pragma unroll
    for (int kc = 0; kc < 2; ++kc) {
      bf16x8 awA, awB;
      if (liveA) {
        const float* ps = &Plds[w][0][lrow][kc * 32 + lk8];
        const f32x4 p0 = *(const f32x4*)ps;
        const f32x4 p1 = *(const f32x4*)(ps + 4);
        #pragma unroll
        for (int j = 0; j < 4; ++j) { awA[j] = (__bf16)p0[j]; awA[4 + j] = (__bf16)p1[j]; }
      }
      {
        const float* ps = &Plds[w][1][lrow][kc * 32 + lk8];
        const f32x4 p0 = *(const f32x4*)ps;
        const f32x4 p1 = *(const f32x4*)(ps + 4);
        #pragma unroll
        for (int j = 0; j < 4; ++j) { awB[j] = (__bf16)p0[j]; awB[4 + j] = (__bf16)p1[j]; }
      }
      #pragma unroll
      for (int nt = 0; nt < 4; ++nt) {
        const bf16x8 bv =
            ld8(Vh + (size_t)(nt * 16 + lrow) * SEQ + kb + kc * 32 + lk8);
        if (liveA) accA[nt] = mfma16(awA, bv, accA[nt]);
        accB[nt] = mfma16(awB, bv, accB[nt]);
      }
    }
  }

  #pragma unroll
  for (int nt = 0; nt < 4; ++nt)
    #pragma unroll
    for (int r = 0; r < 4; ++r) {
      unsafeAtomicAdd(
          &AOf[(size_t)(bb * SEQ + fb0 + g * 4 + r) * DIM + hh * HDIM + nt * 16 + lrow],
          accA[nt][r]);
      unsafeAtomicAdd(
          &AOf[(size_t)(bb * SEQ + fb1 + g * 4 + r) * DIM + hh * HDIM + nt * 16 + lrow],
          accB[nt][r]);
    }
}

// ---------------------------------------------------------------------------
extern "C" void kernel_launch(void* const* d_in, const int* in_sizes, int n_in,
                              void* d_out, int out_size, void* d_ws, size_t ws_size,
                              hipStream_t stream) {
  const float* x  = (const float*)d_in[0];
  const float* Wq = (const float*)d_in[2];
  const float* bq = (const float*)d_in[3];
  const float* Wk = (const float*)d_in[4];
  const float* bk = (const float*)d_in[5];
  const float* Wv = (const float*)d_in[6];
  const float* bv = (const float*)d_in[7];
  const float* Wo = (const float*)d_in[8];
  const float* bo = (const float*)d_in[9];

  char* wsb = (char*)d_ws;
  __bf16* Qb   = (__bf16*)(wsb);                 // [B,H,S,HD] bf16   6 MB
  __bf16* Kb   = (__bf16*)(wsb + 6291456);       // [B,H,S,HD] bf16   6 MB
  __bf16* Vt   = (__bf16*)(wsb + 12582912);      // [B,H,HD,S] bf16   6 MB
  float*  AOf  = (float*)(wsb + 18874368);       // [B*S, D] fp32    12 MB
  float*  sums = (float*)(wsb + 31457280);       // [24,2048] fp32  0.2 MB
  __bf16* WbT  = (__bf16*)(wsb + 31653888);      // [4,768,768] bf16 4.7 MB

  float* out   = (float*)d_out;                  // [2,2048,768] fp32
  float* attnW = out + 3145728;                  // [2,12,2048,2048] fp32
  // xb parked at the head of attnW: read only by qkv_gemm, which completes
  // before attn_sums/attn_wpv overwrite the region.
  __bf16* xb   = (__bf16*)attnW;                 // [4096,768] bf16   6 MB

  zero_f32<<<1024, 256, 0, stream>>>(AOf, (3145728 + 49152) / 4);
  cvt_x<<<1536, 256, 0, stream>>>(x, xb);
  prep_wt<<<dim3(12, 12, 4), 256, 0, stream>>>(Wq, Wk, Wv, Wo, WbT);
  qkv_gemm<<<dim3(12, 64, 3), 256, 0, stream>>>(xb, WbT, bq, bk, bv, Qb, Kb, Vt);
  attn_sums<<<1728, 256, 0, stream>>>(Qb, Kb, sums, attnW);
  attn_wpv<<<960, 256, 0, stream>>>(Qb, Kb, Vt, sums, attnW, AOf);
  out_gemm<<<dim3(12, 64), 256, 0, stream>>>(AOf, WbT, bo, out);
}